// Round 1
// baseline (520.838 us; speedup 1.0000x reference)
//
#include <hip/hip_runtime.h>
#include <stdint.h>

// Problem constants (B=4, L=1024, C=768, H=12, DK=64, MAXREL=7)
// Outputs: z [4,1024,768] fp32 then scores [4,12,1024,1024] fp32, concatenated.

typedef __attribute__((ext_vector_type(4))) float f32x4;
typedef __attribute__((ext_vector_type(4))) int   i32x4;
typedef __attribute__((ext_vector_type(8))) short short8;   // 8 bf16 (4 VGPRs) - MFMA A/B frag
typedef __attribute__((ext_vector_type(4))) unsigned int u32x4;
typedef __attribute__((ext_vector_type(2))) unsigned int u32x2;

__device__ __forceinline__ unsigned short f2bf(float f) {   // fp32 -> bf16, RNE
  unsigned int u = __float_as_uint(f);
  u += 0x7fffu + ((u >> 16) & 1u);
  return (unsigned short)(u >> 16);
}

// ---------------------------------------------------------------------------
// Kernel 1: qx,kx,vx fp32 -> bf16 (flat, 3*4096*768 elems = 2359296 float4s)
__global__ __launch_bounds__(256) void conv_x_kernel(
    const float* __restrict__ qx, const float* __restrict__ kx,
    const float* __restrict__ vx, unsigned short* __restrict__ out) {
  int v = blockIdx.x * 256 + threadIdx.x;       // float4 index, 0..2359295
  int mat = v / 786432;
  int r = v - mat * 786432;
  const float* src = (mat == 0) ? qx : (mat == 1) ? kx : vx;
  f32x4 x = ((const f32x4*)src)[r];
  union { unsigned short s[4]; u32x2 u; } o;
  o.s[0] = f2bf(x[0]); o.s[1] = f2bf(x[1]); o.s[2] = f2bf(x[2]); o.s[3] = f2bf(x[3]);
  ((u32x2*)out)[v] = o.u;
}

// ---------------------------------------------------------------------------
// Kernel 2: W [768k][768n] fp32 -> WT [768n][768k] bf16, for WQ,WK,WV,WO.
__global__ __launch_bounds__(256) void conv_w_kernel(
    const float* __restrict__ w0, const float* __restrict__ w1,
    const float* __restrict__ w2, const float* __restrict__ w3,
    unsigned short* __restrict__ out) {
  __shared__ float T[64][65];                   // [n][k] tile, padded
  int bx = blockIdx.x;
  int mat = bx / 144; int t2 = bx - mat * 144;
  int kt = t2 / 12, nt = t2 - kt * 12;
  int k0 = kt * 64, n0 = nt * 64;
  const float* W = (mat == 0) ? w0 : (mat == 1) ? w1 : (mat == 2) ? w2 : w3;
  unsigned short* WT = out + (size_t)mat * 589824;
  int t = threadIdx.x;
  int lr = t >> 4;            // 0..15
  int lc = (t & 15) * 4;      // 0..60
#pragma unroll
  for (int p = 0; p < 4; p++) {
    int row = p * 16 + lr;    // k-index
    f32x4 x = *(const f32x4*)&W[(size_t)(k0 + row) * 768 + n0 + lc];
    T[lc + 0][row] = x[0]; T[lc + 1][row] = x[1];
    T[lc + 2][row] = x[2]; T[lc + 3][row] = x[3];
  }
  __syncthreads();
#pragma unroll
  for (int p = 0; p < 4; p++) {
    int row = p * 16 + lr;    // n-index
    union { unsigned short s[4]; u32x2 u; } o;
    o.s[0] = f2bf(T[row][lc + 0]); o.s[1] = f2bf(T[row][lc + 1]);
    o.s[2] = f2bf(T[row][lc + 2]); o.s[3] = f2bf(T[row][lc + 3]);
    *(u32x2*)&WT[(size_t)(n0 + row) * 768 + k0 + lc] = o.u;
  }
}

// ---------------------------------------------------------------------------
// Kernel 3: QKV projection GEMM. C[m][n] = X[m][k] * W[k][n] + b[n].
// A = xbf [3][4096][768] bf16, B = WT [3][768n][768k] bf16.
// Epilogue: mat 0 -> q [B,H,L,64]; mat 1 -> k [B,H,L,64]; mat 2 -> vT [B,H,64,L].
// 128x128 tile, BK=64, 256 thr (2x2 waves of 64x64), LDS stride 72 (pad kills conflicts)
__global__ __launch_bounds__(256) void qkv_gemm_kernel(
    const unsigned short* __restrict__ xbf, const unsigned short* __restrict__ wt,
    const float* __restrict__ bq, const float* __restrict__ bk, const float* __restrict__ bv,
    unsigned short* __restrict__ qo, unsigned short* __restrict__ ko,
    unsigned short* __restrict__ vto) {
  __shared__ unsigned short As[128 * 72];
  __shared__ unsigned short Bs[128 * 72];
  int bx = blockIdx.x;
  int mat = bx / 192; int rem = bx - mat * 192;
  int mt = rem / 6, nt = rem - mt * 6;
  int m0 = mt * 128, n0 = nt * 128;
  const unsigned short* A = xbf + (size_t)mat * 4096 * 768;
  const unsigned short* Bm = wt + (size_t)mat * 768 * 768;
  int t = threadIdx.x;
  int wave = t >> 6, lane = t & 63;
  int wm = (wave >> 1) * 64, wn = (wave & 1) * 64;
  int col = lane & 15, quad = lane >> 4;
  int srow = t >> 3;          // 0..31
  int sch = (t & 7) * 8;      // 0..56

  f32x4 acc[4][4];
#pragma unroll
  for (int i = 0; i < 4; i++)
#pragma unroll
    for (int j = 0; j < 4; j++) acc[i][j] = (f32x4){0.f, 0.f, 0.f, 0.f};

  for (int kk = 0; kk < 768; kk += 64) {
#pragma unroll
    for (int p = 0; p < 4; p++) {
      int row = srow + p * 32;
      *(u32x4*)&As[row * 72 + sch] = *(const u32x4*)&A[(size_t)(m0 + row) * 768 + kk + sch];
      *(u32x4*)&Bs[row * 72 + sch] = *(const u32x4*)&Bm[(size_t)(n0 + row) * 768 + kk + sch];
    }
    __syncthreads();
#pragma unroll
    for (int c = 0; c < 2; c++) {
      short8 af[4], bf[4];
#pragma unroll
      for (int i = 0; i < 4; i++) {
        af[i] = *(const short8*)&As[(wm + i * 16 + col) * 72 + c * 32 + quad * 8];
        bf[i] = *(const short8*)&Bs[(wn + i * 16 + col) * 72 + c * 32 + quad * 8];
      }
#pragma unroll
      for (int i = 0; i < 4; i++)
#pragma unroll
        for (int j = 0; j < 4; j++)
          acc[i][j] = __builtin_amdgcn_mfma_f32_16x16x32_bf16(af[i], bf[j], acc[i][j], 0, 0, 0);
    }
    __syncthreads();
  }
  const float* bias = (mat == 0) ? bq : (mat == 1) ? bk : bv;
#pragma unroll
  for (int j = 0; j < 4; j++) {
    int gn = n0 + wn + j * 16 + col;    // n = h*64 + d
    float bsv = bias[gn];
    int h = gn >> 6, d = gn & 63;
#pragma unroll
    for (int i = 0; i < 4; i++) {
#pragma unroll
      for (int r = 0; r < 4; r++) {
        int gm = m0 + wm + i * 16 + quad * 4 + r;   // m = b*1024 + l
        int b = gm >> 10, l = gm & 1023;
        unsigned short v = f2bf(acc[i][j][r] + bsv);
        if (mat == 0)      qo[((size_t)(b * 12 + h) * 1024 + l) * 64 + d] = v;
        else if (mat == 1) ko[((size_t)(b * 12 + h) * 1024 + l) * 64 + d] = v;
        else               vto[((size_t)(b * 12 + h) * 64 + d) * 1024 + l] = v;
      }
    }
  }
}

// ---------------------------------------------------------------------------
// Kernel 4: fused attention (flash-style, scores materialized).
// Computes S^T tiles (A=K rows j, B=Q rows i) so per-lane C-layout holds 4
// CONSECUTIVE j -> dwordx4 preScores/mask loads + scores stores.
// PV as Z^T = V^T * P^T : A-frag from Vs[d][j] (contig), B-frag from Ps[i][j] (contig).
// Block: 64 q-rows (4 waves x 16), j-tiles of 64. Grid idx = it*48 + (b*12+h)
// so XCD (idx%8) = slice%8 -> 6 slices/XCD -> K/V fits per-XCD L2.
__global__ __launch_bounds__(256) void attn_kernel(
    const unsigned short* __restrict__ q, const unsigned short* __restrict__ k,
    const unsigned short* __restrict__ vt, const float* __restrict__ preS,
    const int* __restrict__ maskP, const float* __restrict__ embK,
    const float* __restrict__ embB, float* __restrict__ scores,
    unsigned short* __restrict__ zpre) {
  __shared__ unsigned short Qs[64 * 72];
  __shared__ unsigned short Ks[64 * 72];
  __shared__ unsigned short Vs[64 * 72];    // V^T tile: [d][j]
  __shared__ unsigned short Ps[64 * 72];    // P tile: [i][j]
  __shared__ float eK[16], eB[16];
  int bx = blockIdx.x;
  int slice = bx % 48, it = bx / 48;
  int b = slice / 12, h = slice - b * 12;
  int i0 = it * 64;
  int t = threadIdx.x, wave = t >> 6, lane = t & 63;
  int col = lane & 15, quad = lane >> 4;
  int srow = t >> 3, sch = (t & 7) * 8;

  if (t < 15) { eK[t] = embK[t * 12 + h]; eB[t] = embB[t * 12 + h]; }

  const unsigned short* qbase = q + ((size_t)(b * 12 + h) * 1024 + i0) * 64;
#pragma unroll
  for (int p = 0; p < 2; p++) {
    int row = srow + p * 32;
    *(u32x4*)&Qs[row * 72 + sch] = *(const u32x4*)&qbase[(size_t)row * 64 + sch];
  }
  __syncthreads();
  short8 qf[2];
  qf[0] = *(const short8*)&Qs[(wave * 16 + col) * 72 + quad * 8];
  qf[1] = *(const short8*)&Qs[(wave * 16 + col) * 72 + 32 + quad * 8];

  f32x4 oacc[4];
#pragma unroll
  for (int nd = 0; nd < 4; nd++) oacc[nd] = (f32x4){0.f, 0.f, 0.f, 0.f};
  float m_s = -3.0e38f, l_s = 0.f;

  const unsigned short* kbase = k + (size_t)(b * 12 + h) * 1024 * 64;
  const unsigned short* vbase = vt + (size_t)(b * 12 + h) * 64 * 1024;
  const float* pbase = preS + ((size_t)(b * 12 + h) * 1024 + i0) * 1024;
  const int* mbase = maskP + ((size_t)b * 1024 + i0) * 1024;
  float* sbase = scores + ((size_t)(b * 12 + h) * 1024 + i0) * 1024;
  int lrow = wave * 16 + col;        // this lane's q-row (local)
  int gi = i0 + lrow;                // global q-row

  for (int jt = 0; jt < 16; jt++) {
    int j0 = jt * 64;
#pragma unroll
    for (int p = 0; p < 2; p++) {
      int row = srow + p * 32;
      *(u32x4*)&Ks[row * 72 + sch] = *(const u32x4*)&kbase[(size_t)(j0 + row) * 64 + sch];
      *(u32x4*)&Vs[row * 72 + sch] = *(const u32x4*)&vbase[(size_t)row * 1024 + j0 + sch];
    }
    __syncthreads();

    // S^T tile: rows j (quad*4+reg), cols i (lane&15)
    f32x4 sacc[4];
#pragma unroll
    for (int ns = 0; ns < 4; ns++) sacc[ns] = (f32x4){0.f, 0.f, 0.f, 0.f};
#pragma unroll
    for (int c = 0; c < 2; c++) {
#pragma unroll
      for (int ns = 0; ns < 4; ns++) {
        short8 kf = *(const short8*)&Ks[(ns * 16 + col) * 72 + c * 32 + quad * 8];
        sacc[ns] = __builtin_amdgcn_mfma_f32_16x16x32_bf16(kf, qf[c], sacc[ns], 0, 0, 0);
      }
    }

    // epilogue: scale, rel-pos, preScores, mask, write scores
    float sv[4][4];
#pragma unroll
    for (int ns = 0; ns < 4; ns++) {
      int gj0 = j0 + ns * 16 + quad * 4;
      f32x4 pre = *(const f32x4*)&pbase[(size_t)lrow * 1024 + gj0];
      i32x4 mk = *(const i32x4*)&mbase[(size_t)lrow * 1024 + gj0];
      f32x4 sout;
#pragma unroll
      for (int r = 0; r < 4; r++) {
        int dd = gi - (gj0 + r); dd = dd < 0 ? -dd : dd;
        int idx;
        if (dd <= 7) idx = dd;
        else { idx = 38 - __clz(dd - 7); idx = idx > 14 ? 14 : idx; }  // exact floor(7+log2)
        float s = sacc[ns][r] * 0.125f * eK[idx] + eB[idx] + pre[r];
        if (mk[r] == 0) s = -32768.0f;
        sout[r] = s; sv[ns][r] = s;
      }
      *(f32x4*)&sbase[(size_t)lrow * 1024 + gj0] = sout;
    }

    // online softmax over this lane's 16 j-values, then across quads
    float mx = sv[0][0];
#pragma unroll
    for (int ns = 0; ns < 4; ns++)
#pragma unroll
      for (int r = 0; r < 4; r++) mx = fmaxf(mx, sv[ns][r]);
    mx = fmaxf(mx, __shfl_xor(mx, 16));
    mx = fmaxf(mx, __shfl_xor(mx, 32));
    float mn = fmaxf(m_s, mx);
    float alpha = __expf(m_s - mn);
    float rs = 0.f;
#pragma unroll
    for (int ns = 0; ns < 4; ns++)
#pragma unroll
      for (int r = 0; r < 4; r++) { float p = __expf(sv[ns][r] - mn); sv[ns][r] = p; rs += p; }
    rs += __shfl_xor(rs, 16); rs += __shfl_xor(rs, 32);
    l_s = l_s * alpha + rs;
    m_s = mn;
#pragma unroll
    for (int nd = 0; nd < 4; nd++)
#pragma unroll
      for (int r = 0; r < 4; r++) oacc[nd][r] *= alpha;

    // P tile -> LDS (row i, cols j): 4 consecutive j per pack
#pragma unroll
    for (int ns = 0; ns < 4; ns++) {
      union { unsigned short s[4]; u32x2 u; } pk;
#pragma unroll
      for (int r = 0; r < 4; r++) pk.s[r] = f2bf(sv[ns][r]);
      *(u32x2*)&Ps[(size_t)lrow * 72 + ns * 16 + quad * 4] = pk.u;
    }

    // Z^T += V^T * P^T  (same-wave LDS RAW; compiler inserts lgkmcnt)
#pragma unroll
    for (int c2 = 0; c2 < 2; c2++) {
      short8 pf = *(const short8*)&Ps[(wave * 16 + col) * 72 + c2 * 32 + quad * 8];
#pragma unroll
      for (int nd = 0; nd < 4; nd++) {
        short8 vf = *(const short8*)&Vs[(nd * 16 + col) * 72 + c2 * 32 + quad * 8];
        oacc[nd] = __builtin_amdgcn_mfma_f32_16x16x32_bf16(vf, pf, oacc[nd], 0, 0, 0);
      }
    }
    __syncthreads();
  }

  // z_pre[i][d] = O^T / l  (lane: i=col fixed, d = nd*16 + quad*4 + r)
  float inv = 1.0f / fmaxf(l_s, 1e-30f);
  unsigned short* zb = zpre + ((size_t)(b * 12 + h) * 1024 + i0 + lrow) * 64;
#pragma unroll
  for (int nd = 0; nd < 4; nd++) {
    union { unsigned short s[4]; u32x2 u; } zk;
#pragma unroll
    for (int r = 0; r < 4; r++) zk.s[r] = f2bf(oacc[nd][r] * inv);
    *(u32x2*)&zb[nd * 16 + quad * 4] = zk.u;
  }
}

// ---------------------------------------------------------------------------
// Kernel 5: output projection. z[m][n] = zpre_flat[m][k] * WO[k][n] + WOb[n].
// A[m][k] = zpre[((b*12+h)*1024+l)*64 + d] with m=b*1024+l, k=h*64+d (BK=64=DK).
__global__ __launch_bounds__(256) void out_gemm_kernel(
    const unsigned short* __restrict__ zpre, const unsigned short* __restrict__ wot,
    const float* __restrict__ wob, float* __restrict__ zout) {
  __shared__ unsigned short As[128 * 72];
  __shared__ unsigned short Bs[128 * 72];
  int bx = blockIdx.x;
  int mt = bx / 6, nt = bx - mt * 6;
  int m0 = mt * 128, n0 = nt * 128;
  int t = threadIdx.x;
  int wave = t >> 6, lane = t & 63;
  int wm = (wave >> 1) * 64, wn = (wave & 1) * 64;
  int col = lane & 15, quad = lane >> 4;
  int srow = t >> 3, sch = (t & 7) * 8;

  f32x4 acc[4][4];
#pragma unroll
  for (int i = 0; i < 4; i++)
#pragma unroll
    for (int j = 0; j < 4; j++) acc[i][j] = (f32x4){0.f, 0.f, 0.f, 0.f};

  for (int kk = 0; kk < 768; kk += 64) {
    int hh = kk >> 6;
#pragma unroll
    for (int p = 0; p < 4; p++) {
      int row = srow + p * 32;
      int gm = m0 + row;
      int b = gm >> 10, l = gm & 1023;
      *(u32x4*)&As[row * 72 + sch] =
          *(const u32x4*)&zpre[((size_t)(b * 12 + hh) * 1024 + l) * 64 + sch];
      *(u32x4*)&Bs[row * 72 + sch] = *(const u32x4*)&wot[(size_t)(n0 + row) * 768 + kk + sch];
    }
    __syncthreads();
#pragma unroll
    for (int c = 0; c < 2; c++) {
      short8 af[4], bf[4];
#pragma unroll
      for (int i = 0; i < 4; i++) {
        af[i] = *(const short8*)&As[(wm + i * 16 + col) * 72 + c * 32 + quad * 8];
        bf[i] = *(const short8*)&Bs[(wn + i * 16 + col) * 72 + c * 32 + quad * 8];
      }
#pragma unroll
      for (int i = 0; i < 4; i++)
#pragma unroll
        for (int j = 0; j < 4; j++)
          acc[i][j] = __builtin_amdgcn_mfma_f32_16x16x32_bf16(af[i], bf[j], acc[i][j], 0, 0, 0);
    }
    __syncthreads();
  }
#pragma unroll
  for (int j = 0; j < 4; j++) {
    int gn = n0 + wn + j * 16 + col;
    float bsv = wob[gn];
#pragma unroll
    for (int i = 0; i < 4; i++) {
#pragma unroll
      for (int r = 0; r < 4; r++) {
        int gm = m0 + wm + i * 16 + quad * 4 + r;
        zout[(size_t)gm * 768 + gn] = acc[i][j][r] + bsv;
      }
    }
  }
}

// ---------------------------------------------------------------------------
extern "C" void kernel_launch(void* const* d_in, const int* in_sizes, int n_in,
                              void* d_out, int out_size, void* d_ws, size_t ws_size,
                              hipStream_t stream) {
  const float* qx   = (const float*)d_in[0];
  const float* kx   = (const float*)d_in[1];
  const float* vx   = (const float*)d_in[2];
  const float* WQ_w = (const float*)d_in[3];
  const float* WQ_b = (const float*)d_in[4];
  const float* WK_w = (const float*)d_in[5];
  const float* WK_b = (const float*)d_in[6];
  const float* WV_w = (const float*)d_in[7];
  const float* WV_b = (const float*)d_in[8];
  const float* WO_w = (const float*)d_in[9];
  const float* WO_b = (const float*)d_in[10];
  const float* embK = (const float*)d_in[11];
  const float* embB = (const float*)d_in[12];
  const float* preS = (const float*)d_in[13];
  const int* maskP  = (const int*)d_in[14];

  float* zout = (float*)d_out;                       // [4,1024,768]
  float* scores = zout + 3145728;                    // [4,12,1024,1024]
  // Scratch overlay: bf16 qx/kx/vx live in the scores region (dead before attn writes it)
  unsigned short* xbf = (unsigned short*)scores;     // 18.9 MB

  char* ws = (char*)d_ws;
  unsigned short* wt  = (unsigned short*)(ws);               // 4x768x768 bf16 = 4718592 B
  unsigned short* qb  = (unsigned short*)(ws + 4718592);     // [B,H,L,64] bf16
  unsigned short* kb  = (unsigned short*)(ws + 11010048);    // [B,H,L,64]
  unsigned short* vtb = (unsigned short*)(ws + 17301504);    // [B,H,64,L]
  unsigned short* zp  = (unsigned short*)(ws + 23592960);    // [B,H,L,64]; end = 29884416 B

  conv_x_kernel<<<9216, 256, 0, stream>>>(qx, kx, vx, xbf);
  conv_w_kernel<<<576, 256, 0, stream>>>(WQ_w, WK_w, WV_w, WO_w, wt);
  qkv_gemm_kernel<<<576, 256, 0, stream>>>(xbf, wt, WQ_b, WK_b, WV_b, qb, kb, vtb);
  attn_kernel<<<768, 256, 0, stream>>>(qb, kb, vtb, preS, maskP, embK, embB, scores, zp);
  out_gemm_kernel<<<192, 256, 0, stream>>>(zp, wt + 3 * 589824, WO_b, zout);
}

// Round 2
// 483.339 us; speedup vs baseline: 1.0776x; 1.0776x over previous
//
#include <hip/hip_runtime.h>
#include <stdint.h>

// Problem constants (B=4, L=1024, C=768, H=12, DK=64, MAXREL=7)
// Outputs: z [4,1024,768] fp32 then scores [4,12,1024,1024] fp32, concatenated.

typedef __attribute__((ext_vector_type(4))) float f32x4;
typedef __attribute__((ext_vector_type(4))) int   i32x4;
typedef __attribute__((ext_vector_type(8))) short short8;   // 8 bf16 (4 VGPRs) - MFMA A/B frag
typedef __attribute__((ext_vector_type(4))) unsigned int u32x4;
typedef __attribute__((ext_vector_type(2))) unsigned int u32x2;

__device__ __forceinline__ unsigned short f2bf(float f) {   // fp32 -> bf16, RNE
  unsigned int u = __float_as_uint(f);
  u += 0x7fffu + ((u >> 16) & 1u);
  return (unsigned short)(u >> 16);
}

// ---------------------------------------------------------------------------
// Kernel 1: qx,kx,vx fp32 -> bf16
__global__ __launch_bounds__(256) void conv_x_kernel(
    const float* __restrict__ qx, const float* __restrict__ kx,
    const float* __restrict__ vx, unsigned short* __restrict__ out) {
  int v = blockIdx.x * 256 + threadIdx.x;       // float4 index
  int mat = v / 786432;
  int r = v - mat * 786432;
  const float* src = (mat == 0) ? qx : (mat == 1) ? kx : vx;
  f32x4 x = ((const f32x4*)src)[r];
  union { unsigned short s[4]; u32x2 u; } o;
  o.s[0] = f2bf(x[0]); o.s[1] = f2bf(x[1]); o.s[2] = f2bf(x[2]); o.s[3] = f2bf(x[3]);
  ((u32x2*)out)[v] = o.u;
}

// ---------------------------------------------------------------------------
// Kernel 2: W [768k][768n] fp32 -> WT [768n][768k] bf16, for WQ,WK,WV,WO.
__global__ __launch_bounds__(256) void conv_w_kernel(
    const float* __restrict__ w0, const float* __restrict__ w1,
    const float* __restrict__ w2, const float* __restrict__ w3,
    unsigned short* __restrict__ out) {
  __shared__ float T[64][65];
  int bx = blockIdx.x;
  int mat = bx / 144; int t2 = bx - mat * 144;
  int kt = t2 / 12, nt = t2 - kt * 12;
  int k0 = kt * 64, n0 = nt * 64;
  const float* W = (mat == 0) ? w0 : (mat == 1) ? w1 : (mat == 2) ? w2 : w3;
  unsigned short* WT = out + (size_t)mat * 589824;
  int t = threadIdx.x;
  int lr = t >> 4;
  int lc = (t & 15) * 4;
#pragma unroll
  for (int p = 0; p < 4; p++) {
    int row = p * 16 + lr;
    f32x4 x = *(const f32x4*)&W[(size_t)(k0 + row) * 768 + n0 + lc];
    T[lc + 0][row] = x[0]; T[lc + 1][row] = x[1];
    T[lc + 2][row] = x[2]; T[lc + 3][row] = x[3];
  }
  __syncthreads();
#pragma unroll
  for (int p = 0; p < 4; p++) {
    int row = p * 16 + lr;
    union { unsigned short s[4]; u32x2 u; } o;
    o.s[0] = f2bf(T[row][lc + 0]); o.s[1] = f2bf(T[row][lc + 1]);
    o.s[2] = f2bf(T[row][lc + 2]); o.s[3] = f2bf(T[row][lc + 3]);
    *(u32x2*)&WT[(size_t)(n0 + row) * 768 + k0 + lc] = o.u;
  }
}

// ---------------------------------------------------------------------------
// Kernel 3: QKV projection GEMM, software-pipelined (1 barrier/iter, reg prefetch).
// mat 0 -> q [B,H,L,64]; mat 1 -> k [B,H,L,64]; mat 2 -> vT [B,H,64,L] via LDS
// transpose bounce (coalesced dwordx4 stores; the R1 scatter was ~16x L2 write amp).
__global__ __launch_bounds__(256, 2) void qkv_gemm_kernel(
    const unsigned short* __restrict__ xbf, const unsigned short* __restrict__ wt,
    const float* __restrict__ bq, const float* __restrict__ bk, const float* __restrict__ bv,
    unsigned short* __restrict__ qo, unsigned short* __restrict__ ko,
    unsigned short* __restrict__ vto) {
  __shared__ unsigned short SM[2][2][128 * 72];   // [buf][A/B]
  int bx = blockIdx.x;
  int mat = bx / 192; int rem = bx - mat * 192;
  int mt = rem / 6, nt = rem - mt * 6;
  int m0 = mt * 128, n0 = nt * 128;
  const unsigned short* A = xbf + (size_t)mat * 4096 * 768;
  const unsigned short* Bm = wt + (size_t)mat * 768 * 768;
  int t = threadIdx.x;
  int wave = t >> 6, lane = t & 63;
  int wm = (wave >> 1) * 64, wn = (wave & 1) * 64;
  int col = lane & 15, quad = lane >> 4;
  int srow = t >> 3;
  int sch = (t & 7) * 8;

  f32x4 acc[4][4];
#pragma unroll
  for (int i = 0; i < 4; i++)
#pragma unroll
    for (int j = 0; j < 4; j++) acc[i][j] = (f32x4){0.f, 0.f, 0.f, 0.f};

  u32x4 ra[4], rb[4];
  // prologue: tile 0 -> LDS0; tile 1 -> regs
#pragma unroll
  for (int p = 0; p < 4; p++) {
    ra[p] = *(const u32x4*)&A[(size_t)(m0 + srow + p * 32) * 768 + sch];
    rb[p] = *(const u32x4*)&Bm[(size_t)(n0 + srow + p * 32) * 768 + sch];
  }
#pragma unroll
  for (int p = 0; p < 4; p++) {
    *(u32x4*)&SM[0][0][(srow + p * 32) * 72 + sch] = ra[p];
    *(u32x4*)&SM[0][1][(srow + p * 32) * 72 + sch] = rb[p];
  }
#pragma unroll
  for (int p = 0; p < 4; p++) {
    ra[p] = *(const u32x4*)&A[(size_t)(m0 + srow + p * 32) * 768 + 64 + sch];
    rb[p] = *(const u32x4*)&Bm[(size_t)(n0 + srow + p * 32) * 768 + 64 + sch];
  }
  __syncthreads();

  for (int it = 0; it < 12; ++it) {
    const unsigned short* As = SM[it & 1][0];
    const unsigned short* Bs = SM[it & 1][1];
#pragma unroll
    for (int c = 0; c < 2; c++) {
      short8 af[4], bf[4];
#pragma unroll
      for (int i = 0; i < 4; i++) {
        af[i] = *(const short8*)&As[(wm + i * 16 + col) * 72 + c * 32 + quad * 8];
        bf[i] = *(const short8*)&Bs[(wn + i * 16 + col) * 72 + c * 32 + quad * 8];
      }
#pragma unroll
      for (int i = 0; i < 4; i++)
#pragma unroll
        for (int j = 0; j < 4; j++)
          acc[i][j] = __builtin_amdgcn_mfma_f32_16x16x32_bf16(af[i], bf[j], acc[i][j], 0, 0, 0);
    }
    if (it < 11) {
      unsigned short* An = SM[(it + 1) & 1][0];
      unsigned short* Bn = SM[(it + 1) & 1][1];
#pragma unroll
      for (int p = 0; p < 4; p++) {
        *(u32x4*)&An[(srow + p * 32) * 72 + sch] = ra[p];
        *(u32x4*)&Bn[(srow + p * 32) * 72 + sch] = rb[p];
      }
      if (it < 10) {
        int kk2 = (it + 2) * 64;
#pragma unroll
        for (int p = 0; p < 4; p++) {
          ra[p] = *(const u32x4*)&A[(size_t)(m0 + srow + p * 32) * 768 + kk2 + sch];
          rb[p] = *(const u32x4*)&Bm[(size_t)(n0 + srow + p * 32) * 768 + kk2 + sch];
        }
      }
      __syncthreads();
    }
  }

  if (mat != 2) {
    const float* bias = (mat == 0) ? bq : bk;
    unsigned short* dst = (mat == 0) ? qo : ko;
#pragma unroll
    for (int j = 0; j < 4; j++) {
      int gn = n0 + wn + j * 16 + col;
      float bsv = bias[gn];
      int h = gn >> 6, d = gn & 63;
#pragma unroll
      for (int i = 0; i < 4; i++) {
#pragma unroll
        for (int r = 0; r < 4; r++) {
          int gm = m0 + wm + i * 16 + quad * 4 + r;
          int b = gm >> 10, l = gm & 1023;
          dst[((size_t)(b * 12 + h) * 1024 + l) * 64 + d] = f2bf(acc[i][j][r] + bsv);
        }
      }
    }
  } else {
    // transpose bounce: Tr[n_local][m_local], stride 132 shorts (33792 B <= 36864 SM)
    unsigned short* Tr = &SM[0][0][0];
    __syncthreads();   // all waves done with SM reads (last iter used SM[1]; Tr spans SM[0])
#pragma unroll
    for (int j = 0; j < 4; j++) {
      int n = wn + j * 16 + col;
      float bsv = bv[n0 + n];
#pragma unroll
      for (int i = 0; i < 4; i++) {
        int m = wm + i * 16 + quad * 4;
        union { unsigned short s[4]; u32x2 u; } pk;
#pragma unroll
        for (int r = 0; r < 4; r++) pk.s[r] = f2bf(acc[i][j][r] + bsv);
        *(u32x2*)&Tr[(size_t)n * 132 + m] = pk.u;
      }
    }
    __syncthreads();
#pragma unroll
    for (int p = 0; p < 8; p++) {
      int row = (t >> 4) + p * 16;          // n_local 0..127
      int ch = (t & 15) * 8;                // m_local chunk
      u32x4 val = *(const u32x4*)&Tr[(size_t)row * 132 + ch];
      int gn = n0 + row;
      int h = gn >> 6, d = gn & 63;
      int gm = m0 + ch;
      int b = gm >> 10, l = gm & 1023;
      *(u32x4*)&vto[((size_t)(b * 12 + h) * 64 + d) * 1024 + l] = val;
    }
  }
}

// ---------------------------------------------------------------------------
// Kernel 4: fused attention, software-pipelined.
// One barrier/iter: double-buffered K/V LDS; K/V prefetched 2 iters ahead in
// regs; preS prefetched 1 iter ahead in regs; mask JIT (L2/L3-resident, 12x reuse).
struct KV { u32x4 k0, k1, v0, v1; };

__device__ __forceinline__ void attn_body(
    int jt, const unsigned short* KsC, const unsigned short* VsC,
    unsigned short* KsN, unsigned short* VsN,
    f32x4* preC, f32x4* preN, KV& kvW, KV& kvF,
    const short8* qf, f32x4* oacc, float& m_s, float& l_s,
    const unsigned short* kbase, const unsigned short* vbase,
    const float* pbase, const int* mbase, float* sbase,
    unsigned short* Ps, const float* eK, const float* eB,
    int lrow, int gi, int srow, int sch, int col, int quad, int wave) {
  const int j0 = jt * 64;
  // issue mask loads (tile jt)
  i32x4 mk[4];
#pragma unroll
  for (int ns = 0; ns < 4; ns++)
    mk[ns] = *(const i32x4*)&mbase[(size_t)lrow * 1024 + j0 + ns * 16 + quad * 4];
  // issue preS loads (tile jt+1)
  if (jt < 15) {
    int jp1 = (jt + 1) * 64;
#pragma unroll
    for (int ns = 0; ns < 4; ns++)
      preN[ns] = *(const f32x4*)&pbase[(size_t)lrow * 1024 + jp1 + ns * 16 + quad * 4];
  }
  // issue K/V loads (tile jt+2)
  if (jt < 14) {
    int jp2 = (jt + 2) * 64;
    kvF.k0 = *(const u32x4*)&kbase[(size_t)(jp2 + srow) * 64 + sch];
    kvF.k1 = *(const u32x4*)&kbase[(size_t)(jp2 + srow + 32) * 64 + sch];
    kvF.v0 = *(const u32x4*)&vbase[(size_t)srow * 1024 + jp2 + sch];
    kvF.v1 = *(const u32x4*)&vbase[(size_t)(srow + 32) * 1024 + jp2 + sch];
  }
  // S^T tile: rows j (quad*4+reg), cols i (lane&15)
  f32x4 sacc[4];
#pragma unroll
  for (int ns = 0; ns < 4; ns++) sacc[ns] = (f32x4){0.f, 0.f, 0.f, 0.f};
#pragma unroll
  for (int c = 0; c < 2; c++) {
#pragma unroll
    for (int ns = 0; ns < 4; ns++) {
      short8 kf = *(const short8*)&KsC[(ns * 16 + col) * 72 + c * 32 + quad * 8];
      sacc[ns] = __builtin_amdgcn_mfma_f32_16x16x32_bf16(kf, qf[c], sacc[ns], 0, 0, 0);
    }
  }
  // epilogue: scale, rel-pos, preScores, mask, write scores
  float sv[4][4];
#pragma unroll
  for (int ns = 0; ns < 4; ns++) {
    int gj0 = j0 + ns * 16 + quad * 4;
    f32x4 sout;
#pragma unroll
    for (int r = 0; r < 4; r++) {
      int dd = gi - (gj0 + r); dd = dd < 0 ? -dd : dd;
      int idx;
      if (dd <= 7) idx = dd;
      else { idx = 38 - __clz(dd - 7); idx = idx > 14 ? 14 : idx; }  // exact floor(7+log2)
      float s = sacc[ns][r] * 0.125f * eK[idx] + eB[idx] + preC[ns][r];
      if (mk[ns][r] == 0) s = -32768.0f;
      sout[r] = s; sv[ns][r] = s;
    }
    *(f32x4*)&sbase[(size_t)lrow * 1024 + gj0] = sout;
  }
  // online softmax
  float mx = sv[0][0];
#pragma unroll
  for (int ns = 0; ns < 4; ns++)
#pragma unroll
    for (int r = 0; r < 4; r++) mx = fmaxf(mx, sv[ns][r]);
  mx = fmaxf(mx, __shfl_xor(mx, 16));
  mx = fmaxf(mx, __shfl_xor(mx, 32));
  float mn = fmaxf(m_s, mx);
  float alpha = __expf(m_s - mn);
  float rs = 0.f;
#pragma unroll
  for (int ns = 0; ns < 4; ns++)
#pragma unroll
    for (int r = 0; r < 4; r++) { float p = __expf(sv[ns][r] - mn); sv[ns][r] = p; rs += p; }
  rs += __shfl_xor(rs, 16); rs += __shfl_xor(rs, 32);
  l_s = l_s * alpha + rs;
  m_s = mn;
#pragma unroll
  for (int nd = 0; nd < 4; nd++)
#pragma unroll
    for (int r = 0; r < 4; r++) oacc[nd][r] *= alpha;
  // P tile -> LDS (wave-private rows; same-wave RAW, compiler inserts lgkmcnt)
#pragma unroll
  for (int ns = 0; ns < 4; ns++) {
    union { unsigned short s[4]; u32x2 u; } pk;
#pragma unroll
    for (int r = 0; r < 4; r++) pk.s[r] = f2bf(sv[ns][r]);
    *(u32x2*)&Ps[(size_t)lrow * 72 + ns * 16 + quad * 4] = pk.u;
  }
  // Z^T += V^T * P^T
#pragma unroll
  for (int c2 = 0; c2 < 2; c2++) {
    short8 pf = *(const short8*)&Ps[(wave * 16 + col) * 72 + c2 * 32 + quad * 8];
#pragma unroll
    for (int nd = 0; nd < 4; nd++) {
      short8 vf = *(const short8*)&VsC[(nd * 16 + col) * 72 + c2 * 32 + quad * 8];
      oacc[nd] = __builtin_amdgcn_mfma_f32_16x16x32_bf16(vf, pf, oacc[nd], 0, 0, 0);
    }
  }
  // stage tile jt+1 -> alternate buffers; single barrier per iteration
  if (jt < 15) {
    *(u32x4*)&KsN[srow * 72 + sch] = kvW.k0;
    *(u32x4*)&KsN[(srow + 32) * 72 + sch] = kvW.k1;
    *(u32x4*)&VsN[srow * 72 + sch] = kvW.v0;
    *(u32x4*)&VsN[(srow + 32) * 72 + sch] = kvW.v1;
    __syncthreads();
  }
}

__global__ __launch_bounds__(256, 3) void attn_kernel(
    const unsigned short* __restrict__ q, const unsigned short* __restrict__ k,
    const unsigned short* __restrict__ vt, const float* __restrict__ preS,
    const int* __restrict__ maskP, const float* __restrict__ embK,
    const float* __restrict__ embB, float* __restrict__ scores,
    unsigned short* __restrict__ zpre) {
  __shared__ unsigned short Qs[64 * 72];        // aliased as Ps after qf read (wave-private rows)
  __shared__ unsigned short KsB[2][64 * 72];
  __shared__ unsigned short VsB[2][64 * 72];
  __shared__ float eKs[16], eBs[16];
  int bx = blockIdx.x;
  int slice = bx % 48, it = bx / 48;
  int b = slice / 12, h = slice - b * 12;
  int i0 = it * 64;
  int t = threadIdx.x, wave = t >> 6, lane = t & 63;
  int col = lane & 15, quad = lane >> 4;
  int srow = t >> 3, sch = (t & 7) * 8;

  if (t < 15) { eKs[t] = embK[t * 12 + h]; eBs[t] = embB[t * 12 + h]; }

  const unsigned short* qbase = q + ((size_t)(b * 12 + h) * 1024 + i0) * 64;
  const unsigned short* kbase = k + (size_t)(b * 12 + h) * 1024 * 64;
  const unsigned short* vbase = vt + (size_t)(b * 12 + h) * 64 * 1024;
  const float* pbase = preS + ((size_t)(b * 12 + h) * 1024 + i0) * 1024;
  const int* mbase = maskP + ((size_t)b * 1024 + i0) * 1024;
  float* sbase = scores + ((size_t)(b * 12 + h) * 1024 + i0) * 1024;
  int lrow = wave * 16 + col;
  int gi = i0 + lrow;

#pragma unroll
  for (int p = 0; p < 2; p++) {
    int row = srow + p * 32;
    *(u32x4*)&Qs[row * 72 + sch] = *(const u32x4*)&qbase[(size_t)row * 64 + sch];
  }
  __syncthreads();
  short8 qf[2];
  qf[0] = *(const short8*)&Qs[(wave * 16 + col) * 72 + quad * 8];
  qf[1] = *(const short8*)&Qs[(wave * 16 + col) * 72 + 32 + quad * 8];

  f32x4 oacc[4];
#pragma unroll
  for (int nd = 0; nd < 4; nd++) oacc[nd] = (f32x4){0.f, 0.f, 0.f, 0.f};
  float m_s = -3.0e38f, l_s = 0.f;

  // prologue: tile0 -> LDS[0]; preS(0) -> regs; tile1 -> regs
  KV kvA, kvB;
  f32x4 preA[4], preB[4];
  kvA.k0 = *(const u32x4*)&kbase[(size_t)srow * 64 + sch];
  kvA.k1 = *(const u32x4*)&kbase[(size_t)(srow + 32) * 64 + sch];
  kvA.v0 = *(const u32x4*)&vbase[(size_t)srow * 1024 + sch];
  kvA.v1 = *(const u32x4*)&vbase[(size_t)(srow + 32) * 1024 + sch];
  *(u32x4*)&KsB[0][srow * 72 + sch] = kvA.k0;
  *(u32x4*)&KsB[0][(srow + 32) * 72 + sch] = kvA.k1;
  *(u32x4*)&VsB[0][srow * 72 + sch] = kvA.v0;
  *(u32x4*)&VsB[0][(srow + 32) * 72 + sch] = kvA.v1;
#pragma unroll
  for (int ns = 0; ns < 4; ns++)
    preA[ns] = *(const f32x4*)&pbase[(size_t)lrow * 1024 + ns * 16 + quad * 4];
  kvB.k0 = *(const u32x4*)&kbase[(size_t)(64 + srow) * 64 + sch];
  kvB.k1 = *(const u32x4*)&kbase[(size_t)(64 + srow + 32) * 64 + sch];
  kvB.v0 = *(const u32x4*)&vbase[(size_t)srow * 1024 + 64 + sch];
  kvB.v1 = *(const u32x4*)&vbase[(size_t)(srow + 32) * 1024 + 64 + sch];
  __syncthreads();

  unsigned short* Ps = Qs;   // Qs dead after qf; Ps rows are wave-private
  for (int jt = 0; jt < 16; jt += 2) {
    attn_body(jt,     KsB[0], VsB[0], KsB[1], VsB[1], preA, preB, kvB, kvA,
              qf, oacc, m_s, l_s, kbase, vbase, pbase, mbase, sbase,
              Ps, eKs, eBs, lrow, gi, srow, sch, col, quad, wave);
    attn_body(jt + 1, KsB[1], VsB[1], KsB[0], VsB[0], preB, preA, kvA, kvB,
              qf, oacc, m_s, l_s, kbase, vbase, pbase, mbase, sbase,
              Ps, eKs, eBs, lrow, gi, srow, sch, col, quad, wave);
  }

  float inv = 1.0f / fmaxf(l_s, 1e-30f);
  unsigned short* zb = zpre + ((size_t)(b * 12 + h) * 1024 + i0 + lrow) * 64;
#pragma unroll
  for (int nd = 0; nd < 4; nd++) {
    union { unsigned short s[4]; u32x2 u; } zk;
#pragma unroll
    for (int r = 0; r < 4; r++) zk.s[r] = f2bf(oacc[nd][r] * inv);
    *(u32x2*)&zb[nd * 16 + quad * 4] = zk.u;
  }
}

// ---------------------------------------------------------------------------
// Kernel 5: output projection, 64x64 tiles -> 768 blocks (3/CU), pipelined.
__global__ __launch_bounds__(256, 3) void out_gemm_kernel(
    const unsigned short* __restrict__ zpre, const unsigned short* __restrict__ wot,
    const float* __restrict__ wob, float* __restrict__ zout) {
  __shared__ unsigned short SM[2][2][64 * 72];
  int bx = blockIdx.x;
  int mt = bx / 12, nt = bx - mt * 12;
  int m0 = mt * 64, n0 = nt * 64;
  int t = threadIdx.x;
  int wave = t >> 6, lane = t & 63;
  int wm = (wave >> 1) * 32, wn = (wave & 1) * 32;
  int col = lane & 15, quad = lane >> 4;
  int srow = t >> 3, sch = (t & 7) * 8;
  int gmA0 = m0 + srow, gmA1 = m0 + srow + 32;
  int bA0 = gmA0 >> 10, lA0 = gmA0 & 1023;
  int bA1 = gmA1 >> 10, lA1 = gmA1 & 1023;

  f32x4 acc[2][2];
#pragma unroll
  for (int i = 0; i < 2; i++)
#pragma unroll
    for (int j = 0; j < 2; j++) acc[i][j] = (f32x4){0.f, 0.f, 0.f, 0.f};

  u32x4 ra[2], rb[2];
  // prologue: tile0 -> LDS0 (hh=0), tile1 -> regs
  ra[0] = *(const u32x4*)&zpre[((size_t)(bA0 * 12 + 0) * 1024 + lA0) * 64 + sch];
  ra[1] = *(const u32x4*)&zpre[((size_t)(bA1 * 12 + 0) * 1024 + lA1) * 64 + sch];
  rb[0] = *(const u32x4*)&wot[(size_t)(n0 + srow) * 768 + sch];
  rb[1] = *(const u32x4*)&wot[(size_t)(n0 + srow + 32) * 768 + sch];
  *(u32x4*)&SM[0][0][srow * 72 + sch] = ra[0];
  *(u32x4*)&SM[0][0][(srow + 32) * 72 + sch] = ra[1];
  *(u32x4*)&SM[0][1][srow * 72 + sch] = rb[0];
  *(u32x4*)&SM[0][1][(srow + 32) * 72 + sch] = rb[1];
  ra[0] = *(const u32x4*)&zpre[((size_t)(bA0 * 12 + 1) * 1024 + lA0) * 64 + sch];
  ra[1] = *(const u32x4*)&zpre[((size_t)(bA1 * 12 + 1) * 1024 + lA1) * 64 + sch];
  rb[0] = *(const u32x4*)&wot[(size_t)(n0 + srow) * 768 + 64 + sch];
  rb[1] = *(const u32x4*)&wot[(size_t)(n0 + srow + 32) * 768 + 64 + sch];
  __syncthreads();

  for (int it = 0; it < 12; ++it) {
    const unsigned short* As = SM[it & 1][0];
    const unsigned short* Bs = SM[it & 1][1];
#pragma unroll
    for (int c = 0; c < 2; c++) {
      short8 af[2], bf[2];
#pragma unroll
      for (int i = 0; i < 2; i++) {
        af[i] = *(const short8*)&As[(wm + i * 16 + col) * 72 + c * 32 + quad * 8];
        bf[i] = *(const short8*)&Bs[(wn + i * 16 + col) * 72 + c * 32 + quad * 8];
      }
#pragma unroll
      for (int i = 0; i < 2; i++)
#pragma unroll
        for (int j = 0; j < 2; j++)
          acc[i][j] = __builtin_amdgcn_mfma_f32_16x16x32_bf16(af[i], bf[j], acc[i][j], 0, 0, 0);
    }
    if (it < 11) {
      unsigned short* An = SM[(it + 1) & 1][0];
      unsigned short* Bn = SM[(it + 1) & 1][1];
      *(u32x4*)&An[srow * 72 + sch] = ra[0];
      *(u32x4*)&An[(srow + 32) * 72 + sch] = ra[1];
      *(u32x4*)&Bn[srow * 72 + sch] = rb[0];
      *(u32x4*)&Bn[(srow + 32) * 72 + sch] = rb[1];
      if (it < 10) {
        int hh = it + 2;
        ra[0] = *(const u32x4*)&zpre[((size_t)(bA0 * 12 + hh) * 1024 + lA0) * 64 + sch];
        ra[1] = *(const u32x4*)&zpre[((size_t)(bA1 * 12 + hh) * 1024 + lA1) * 64 + sch];
        rb[0] = *(const u32x4*)&wot[(size_t)(n0 + srow) * 768 + hh * 64 + sch];
        rb[1] = *(const u32x4*)&wot[(size_t)(n0 + srow + 32) * 768 + hh * 64 + sch];
      }
      __syncthreads();
    }
  }
#pragma unroll
  for (int j = 0; j < 2; j++) {
    int gn = n0 + wn + j * 16 + col;
    float bsv = wob[gn];
#pragma unroll
    for (int i = 0; i < 2; i++) {
#pragma unroll
      for (int r = 0; r < 4; r++) {
        int gm = m0 + wm + i * 16 + quad * 4 + r;
        zout[(size_t)gm * 768 + gn] = acc[i][j][r] + bsv;
      }
    }
  }
}

// ---------------------------------------------------------------------------
extern "C" void kernel_launch(void* const* d_in, const int* in_sizes, int n_in,
                              void* d_out, int out_size, void* d_ws, size_t ws_size,
                              hipStream_t stream) {
  const float* qx   = (const float*)d_in[0];
  const float* kx   = (const float*)d_in[1];
  const float* vx   = (const float*)d_in[2];
  const float* WQ_w = (const float*)d_in[3];
  const float* WQ_b = (const float*)d_in[4];
  const float* WK_w = (const float*)d_in[5];
  const float* WK_b = (const float*)d_in[6];
  const float* WV_w = (const float*)d_in[7];
  const float* WV_b = (const float*)d_in[8];
  const float* WO_w = (const float*)d_in[9];
  const float* WO_b = (const float*)d_in[10];
  const float* embK = (const float*)d_in[11];
  const float* embB = (const float*)d_in[12];
  const float* preS = (const float*)d_in[13];
  const int* maskP  = (const int*)d_in[14];

  float* zout = (float*)d_out;                       // [4,1024,768]
  float* scores = zout + 3145728;                    // [4,12,1024,1024]
  unsigned short* xbf = (unsigned short*)scores;     // scratch overlay (dead before attn)

  char* ws = (char*)d_ws;
  unsigned short* wt  = (unsigned short*)(ws);               // 4x768x768 bf16
  unsigned short* qb  = (unsigned short*)(ws + 4718592);     // [B,H,L,64] bf16
  unsigned short* kb  = (unsigned short*)(ws + 11010048);    // [B,H,L,64]
  unsigned short* vtb = (unsigned short*)(ws + 17301504);    // [B,H,64,L]
  unsigned short* zp  = (unsigned short*)(ws + 23592960);    // [B,H,L,64]

  conv_x_kernel<<<9216, 256, 0, stream>>>(qx, kx, vx, xbf);
  conv_w_kernel<<<576, 256, 0, stream>>>(WQ_w, WK_w, WV_w, WO_w, wt);
  qkv_gemm_kernel<<<576, 256, 0, stream>>>(xbf, wt, WQ_b, WK_b, WV_b, qb, kb, vtb);
  attn_kernel<<<768, 256, 0, stream>>>(qb, kb, vtb, preS, maskP, embK, embB, scores, zp);
  out_gemm_kernel<<<192 * 4, 256, 0, stream>>>(zp, wt + 3 * 589824, WO_b, zout);
}